// Round 9
// baseline (208.580 us; speedup 1.0000x reference)
//
#include <hip/hip_runtime.h>

#define N_NODES 50000
#define N_EDGES 800000
#define DIM 64
#define N_LAYERS 3
#define N_GRAPHS 256
#define BN_EPS 1e-5f
#define D3 (DIM * N_LAYERS)
#define N_PART 8
#define NBKT 782          // ceil(50000/64) destination buckets
#define NPB 196           // partition blocks (4096 edges each)
#define ECAP 2048         // fixed capacity per bucket (mean 1023, sigma ~32)
#define CVT_BLOCKS 3125   // convert_x blocks (800,000 float4 / 256)
#define PREP_BLOCKS 96    // prep_weights blocks (24,576 / 256)
#define SZ_STR 68

typedef __attribute__((ext_vector_type(8))) short short8;
typedef __attribute__((ext_vector_type(4))) float floatx4;

// ---------------------------------------------------------- bf16 split utils
__device__ inline unsigned short bf16_rn(float f) {
    unsigned u = __float_as_uint(f);
    u += 0x7FFF + ((u >> 16) & 1);
    return (unsigned short)(u >> 16);
}
__device__ inline float bf16_f(unsigned short b) {
    return __uint_as_float(((unsigned)b) << 16);
}
__device__ inline void split8(float4 a, float4 b, short8* hi, short8* lo) {
    float v[8] = {a.x, a.y, a.z, a.w, b.x, b.y, b.z, b.w};
#pragma unroll
    for (int i = 0; i < 8; i++) {
        unsigned short h = bf16_rn(v[i]);
        (*hi)[i] = (short)h;
        (*lo)[i] = (short)bf16_rn(v[i] - bf16_f(h));
    }
}

// ===== single-pass setup: LDS hist -> atomic chunk reservation -> chunked
// scatter (blocks [0,NPB)) + x->bf16 convert + weight prep + cntg.
// galloc[] (pre-zeroed) accumulates bucket totals; its final value == bcnt.
__global__ __launch_bounds__(256) void setup_scatter(
    const int* __restrict__ src, const int* __restrict__ dst,
    int* __restrict__ galloc,
    unsigned* __restrict__ ebuf,
    const float* __restrict__ x, unsigned short* __restrict__ xb,
    const float* __restrict__ W1, const float* __restrict__ W2,
    unsigned short* __restrict__ wf,
    const int* __restrict__ batch, int* __restrict__ cntg) {
    int blk = blockIdx.x, tid = threadIdx.x;

    if (blk < NPB) {                      // ---- hist + reserve + scatter
        __shared__ int hcnt[NBKT];
        __shared__ int loff[NBKT];
        for (int i = tid; i < NBKT; i += 256) hcnt[i] = 0;
        __syncthreads();
        int base = blk * 4096;
#pragma unroll
        for (int k = 0; k < 16; k++) {
            int e = base + k * 256 + tid;
            if (e < N_EDGES) atomicAdd(&hcnt[dst[e] >> 6], 1);   // LDS atomic
        }
        __syncthreads();
        for (int i = tid; i < NBKT; i += 256) {
            int c = hcnt[i];
            loff[i] = c ? atomicAdd(&galloc[i], c) : 0;   // global chunk reserve
        }
        __syncthreads();
#pragma unroll
        for (int k = 0; k < 16; k++) {
            int e = base + k * 256 + tid;
            if (e < N_EDGES) {
                int d = dst[e];
                int b = d >> 6;
                int pos = atomicAdd(&loff[b], 1);          // LDS atomic
                ebuf[(size_t)b * ECAP + pos] = ((unsigned)src[e] << 6) | (unsigned)(d & 63);
            }
        }
        return;
    }
    int sb = blk - NPB;
    if (sb < CVT_BLOCKS) {                // ---- convert x to bf16
        int i = sb * 256 + tid;
        float4 v = ((const float4*)x)[i];
        ushort4 o;
        o.x = bf16_rn(v.x); o.y = bf16_rn(v.y);
        o.z = bf16_rn(v.z); o.w = bf16_rn(v.w);
        ((ushort4*)xb)[i] = o;
        return;
    }
    sb -= CVT_BLOCKS;
    if (sb < PREP_BLOCKS) {               // ---- pack weight fragments
        int idx = sb * 256 + tid;
        int j    = idx & 7;
        int lane = (idx >> 3) & 63;
        int ks   = (idx >> 9) & 1;
        int nt   = (idx >> 10) & 3;
        int gemm = (idx >> 12) & 1;
        int layer = idx >> 13;
        int n = nt * 16 + (lane & 15);
        int k = ks * 32 + (lane >> 4) * 8 + j;
        const float* W = (gemm ? W2 : W1) + (size_t)layer * DIM * DIM;
        float w = W[k * DIM + n];
        unsigned short hi = bf16_rn(w);
        unsigned short lo = bf16_rn(w - bf16_f(hi));
        size_t base = ((size_t)layer * 2 + gemm) * 8192;
        int f = nt * 2 + ks;
        wf[base + f * 512 + lane * 8 + j]        = hi;
        wf[base + 4096 + f * 512 + lane * 8 + j] = lo;
        return;
    }
    // ---- per-graph node counts via binary search (batch sorted)
    int g = tid;
    int lo = 0, hi = N_NODES;
    while (lo < hi) { int mid = (lo + hi) >> 1; if (batch[mid] < g) lo = mid + 1; else hi = mid; }
    int start = lo;
    lo = 0; hi = N_NODES;
    while (lo < hi) { int mid = (lo + hi) >> 1; if (batch[mid] < g + 1) lo = mid + 1; else hi = mid; }
    cntg[g] = lo - start;
}

// ===================== fused per-layer kernel =====================
// Block = 64 nodes = one CSR bucket. LDS ~19.7 KB (sCsr dropped — gather
// reads indices from L2-resident csr, 8-lane broadcast). launch_bounds
// (256,6) targets 6 blocks/CU = 24 waves/CU for gather latency hiding.
// H-tile overlays sZ (wave w's H rows == wave w's own sZ rows).
__global__ __launch_bounds__(256, 6) void layer_fused(
    const unsigned short* __restrict__ hb,   // input node rows (bf16)
    unsigned short* __restrict__ zb,         // output node rows (bf16), if write_z
    const unsigned* __restrict__ ebuf, const int* __restrict__ bcnt,
    int* __restrict__ csr, int* __restrict__ rp2,
    const float* __restrict__ spPrev,        // null for layer 0
    const float* __restrict__ gammaP, const float* __restrict__ betaP,
    const unsigned short* __restrict__ wfL,
    const float* __restrict__ B1, const float* __restrict__ B2,
    float* __restrict__ sums_part, float* __restrict__ praw,
    const int* __restrict__ batch, int write_z, int do_sort) {
    __shared__ __align__(16) float sZ[64 * SZ_STR];   // 17408 B (gather out + H overlay)
    __shared__ float sSS[2 * DIM];
    __shared__ float sSum[2 * DIM];
    __shared__ int   sRP[65];               // bucket-relative row pointers
    __shared__ int   sBatch[64];
    __shared__ int   cnt[64], basea[64], fill[64];

    int tid = threadIdx.x;
    int blk = blockIdx.x;
    int blk0 = blk * 64;

    if (tid < 2 * DIM) sSum[tid] = 0.f;
    if (tid < 64) sBatch[tid] = (blk0 + tid < N_NODES) ? batch[blk0 + tid] : -1;

    if (do_sort) {
        // ---------------- bucket counting sort (layer 0) ----------------
        int T = bcnt[blk];
        unsigned* ent = (unsigned*)sZ;       // raw-entry staging (8KB of 17.4KB)
        const unsigned* eb = ebuf + (size_t)blk * ECAP;
        if (tid < 64) cnt[tid] = 0;
        for (int i = tid; i < T; i += 256) ent[i] = eb[i];
        __syncthreads();
        for (int i = tid; i < T; i += 256) atomicAdd(&cnt[ent[i] & 63], 1);
        __syncthreads();
        if (tid < 64) {
            int v = cnt[tid], xp = v;
#pragma unroll
            for (int off = 1; off < 64; off <<= 1) {
                int y = __shfl_up(xp, off);
                if (tid >= off) xp += y;
            }
            basea[tid] = xp - v;
            fill[tid] = 0;
            sRP[tid] = xp - v;
            rp2[blk * 65 + tid] = blk * ECAP + xp - v;
            if (tid == 63) { sRP[64] = xp; rp2[blk * 65 + 64] = blk * ECAP + xp; }
        }
        __syncthreads();
        for (int i = tid; i < T; i += 256) {
            unsigned e = ent[i];
            int c = e & 63;
            int pos = basea[c] + atomicAdd(&fill[c], 1);
            csr[blk * ECAP + pos] = (int)(e >> 6);   // re-read below after barrier
        }
        __syncthreads();     // drains vmcnt: csr writes visible to own block
    } else {
        // ---------------- stage row pointers; BN finalize ----
        if (tid < 65) sRP[tid] = rp2[blk * 65 + tid] - blk * ECAP;
        float* sRed = sZ;                    // scratch (sZ rewritten by gather)
        if (spPrev && tid < 2 * DIM) {
            float s = 0.f;
#pragma unroll
            for (int p = 0; p < N_PART; p++) s += spPrev[p * 2 * DIM + tid];
            sRed[tid] = s;
        }
        __syncthreads();
        if (spPrev && tid < DIM) {
            const float inv_n = 1.0f / (float)N_NODES;
            float mu  = sRed[tid] * inv_n;
            float var = sRed[DIM + tid] * inv_n - mu * mu;
            float sc  = gammaP[tid] / sqrtf(var + BN_EPS);
            sSS[tid]       = sc;
            sSS[DIM + tid] = betaP[tid] - mu * sc;
        }
        __syncthreads();
    }

    // ---------------- Phase B: gather into sZ ----------------
    {
        const int* cs = csr + (size_t)blk * ECAP;   // L2-resident indices
        int c8 = tid & 7, grp = tid >> 3;    // 32 groups of 8 lanes
        const bool aff = (spPrev != nullptr);
#pragma unroll
        for (int p = 0; p < 2; ++p) {
            int t = grp + 32 * p;
            int nodeg = blk0 + t;
            float a[8];
            if (nodeg < N_NODES) {
                int e0 = sRP[t], end = sRP[t + 1];
                short8 sv = *(const short8*)&hb[(size_t)nodeg * DIM + c8 * 8];
#pragma unroll
                for (int i = 0; i < 8; i++) a[i] = bf16_f((unsigned short)sv[i]);
                int e = e0;
                for (; e + 4 <= end; e += 4) {
                    int i0 = cs[e], i1 = cs[e + 1], i2 = cs[e + 2], i3 = cs[e + 3];
                    short8 r0 = *(const short8*)&hb[(size_t)i0 * DIM + c8 * 8];
                    short8 r1 = *(const short8*)&hb[(size_t)i1 * DIM + c8 * 8];
                    short8 r2 = *(const short8*)&hb[(size_t)i2 * DIM + c8 * 8];
                    short8 r3 = *(const short8*)&hb[(size_t)i3 * DIM + c8 * 8];
#pragma unroll
                    for (int i = 0; i < 8; i++)
                        a[i] += (bf16_f((unsigned short)r0[i]) + bf16_f((unsigned short)r1[i]))
                              + (bf16_f((unsigned short)r2[i]) + bf16_f((unsigned short)r3[i]));
                }
                for (; e < end; ++e) {
                    int i0 = cs[e];
                    short8 r0 = *(const short8*)&hb[(size_t)i0 * DIM + c8 * 8];
#pragma unroll
                    for (int i = 0; i < 8; i++) a[i] += bf16_f((unsigned short)r0[i]);
                }
                if (aff) {
                    float degf = 1.f + (float)(end - e0);
#pragma unroll
                    for (int i = 0; i < 8; i++)
                        a[i] = fmaf(a[i], sSS[c8 * 8 + i], degf * sSS[DIM + c8 * 8 + i]);
                }
            } else {
#pragma unroll
                for (int i = 0; i < 8; i++) a[i] = 0.f;
            }
            float4 o1, o2;
            o1.x = a[0]; o1.y = a[1]; o1.z = a[2]; o1.w = a[3];
            o2.x = a[4]; o2.y = a[5]; o2.z = a[6]; o2.w = a[7];
            *(float4*)&sZ[t * SZ_STR + c8 * 8]     = o1;
            *(float4*)&sZ[t * SZ_STR + c8 * 8 + 4] = o2;
        }
    }
    __syncthreads();

    // ---------------- Phase C: MFMA MLP ----------------
    int wave = tid >> 6, lane = tid & 63;
    int m = lane & 15, quad = lane >> 4;
    int row0 = blk0 + wave * 16;
    int lrow = wave * 16 + m;

    float4 a0 = *(const float4*)&sZ[lrow * SZ_STR + quad * 8];
    float4 a1 = *(const float4*)&sZ[lrow * SZ_STR + quad * 8 + 4];
    float4 a2 = *(const float4*)&sZ[lrow * SZ_STR + 32 + quad * 8];
    float4 a3 = *(const float4*)&sZ[lrow * SZ_STR + 32 + quad * 8 + 4];
    short8 Ah0, Al0, Ah1, Al1;
    split8(a0, a1, &Ah0, &Al0);
    split8(a2, a3, &Ah1, &Al1);

    floatx4 acc[4];
#pragma unroll
    for (int nt = 0; nt < 4; nt++) acc[nt] = (floatx4){0.f, 0.f, 0.f, 0.f};
#pragma unroll
    for (int nt = 0; nt < 4; nt++) {
#pragma unroll
        for (int ks = 0; ks < 2; ks++) {
            const short8 Bh = *(const short8*)(wfL + (nt * 2 + ks) * 512 + lane * 8);
            const short8 Bl = *(const short8*)(wfL + 4096 + (nt * 2 + ks) * 512 + lane * 8);
            short8 Ahf = ks ? Ah1 : Ah0;
            short8 Alf = ks ? Al1 : Al0;
            acc[nt] = __builtin_amdgcn_mfma_f32_16x16x32_bf16(Ahf, Bh, acc[nt], 0, 0, 0);
            acc[nt] = __builtin_amdgcn_mfma_f32_16x16x32_bf16(Ahf, Bl, acc[nt], 0, 0, 0);
            acc[nt] = __builtin_amdgcn_mfma_f32_16x16x32_bf16(Alf, Bh, acc[nt], 0, 0, 0);
        }
    }

    // all waves' A-fragments are in registers; safe to overlay H on own sZ rows
    __syncthreads();
    float* Hs = sZ + (size_t)(wave * 16) * SZ_STR;   // wave w's own 16 rows
#pragma unroll
    for (int nt = 0; nt < 4; nt++) {
        int col = nt * 16 + m;
        float b = B1[col];
#pragma unroll
        for (int r = 0; r < 4; r++) {
            int lr = quad * 4 + r;
            Hs[lr * SZ_STR + col] = fmaxf(acc[nt][r] + b, 0.f);
        }
    }
    float4 h0 = *(const float4*)&Hs[m * SZ_STR + quad * 8];
    float4 h1 = *(const float4*)&Hs[m * SZ_STR + quad * 8 + 4];
    float4 h2 = *(const float4*)&Hs[m * SZ_STR + 32 + quad * 8];
    float4 h3 = *(const float4*)&Hs[m * SZ_STR + 32 + quad * 8 + 4];
    short8 Hh0, Hl0, Hh1, Hl1;
    split8(h0, h1, &Hh0, &Hl0);
    split8(h2, h3, &Hh1, &Hl1);

    floatx4 acc2[4];
#pragma unroll
    for (int nt = 0; nt < 4; nt++) acc2[nt] = (floatx4){0.f, 0.f, 0.f, 0.f};
    const unsigned short* wg2 = wfL + 8192;
#pragma unroll
    for (int nt = 0; nt < 4; nt++) {
#pragma unroll
        for (int ks = 0; ks < 2; ks++) {
            const short8 Bh = *(const short8*)(wg2 + (nt * 2 + ks) * 512 + lane * 8);
            const short8 Bl = *(const short8*)(wg2 + 4096 + (nt * 2 + ks) * 512 + lane * 8);
            short8 Ahf = ks ? Hh1 : Hh0;
            short8 Alf = ks ? Hl1 : Hl0;
            acc2[nt] = __builtin_amdgcn_mfma_f32_16x16x32_bf16(Ahf, Bh, acc2[nt], 0, 0, 0);
            acc2[nt] = __builtin_amdgcn_mfma_f32_16x16x32_bf16(Ahf, Bl, acc2[nt], 0, 0, 0);
            acc2[nt] = __builtin_amdgcn_mfma_f32_16x16x32_bf16(Alf, Bh, acc2[nt], 0, 0, 0);
        }
    }

    // ---- epilogue: bf16 z write + BN partials + per-graph raw pooling
    int widx = wave * 16;
    int gfirst = sBatch[widx], glast = sBatch[widx + 15];
    bool uni = (gfirst == glast) && (gfirst >= 0);
#pragma unroll
    for (int nt = 0; nt < 4; nt++) {
        int col = nt * 16 + m;
        float b = B2[col];
        float vv[4];
        float s = 0.f, s2 = 0.f;
#pragma unroll
        for (int r = 0; r < 4; r++) {
            int gr = row0 + quad * 4 + r;
            float v = fmaxf(acc2[nt][r] + b, 0.f);
            if (gr < N_NODES) {
                if (write_z) zb[(size_t)gr * DIM + col] = bf16_rn(v);
                s += v;
                s2 = fmaf(v, v, s2);
                vv[r] = v;
            } else {
                vv[r] = 0.f;
            }
        }
        float sf = s, s2f = s2;
        sf  += __shfl_xor(sf, 16);  sf  += __shfl_xor(sf, 32);
        s2f += __shfl_xor(s2f, 16); s2f += __shfl_xor(s2f, 32);
        if (quad == 0) {
            atomicAdd(&sSum[col], sf);
            atomicAdd(&sSum[DIM + col], s2f);
            if (uni) atomicAdd(&praw[(size_t)gfirst * DIM + col], sf);
        }
        if (!uni) {
            int cur = -1; float run = 0.f;
#pragma unroll
            for (int r = 0; r < 4; r++) {
                int g = sBatch[widx + quad * 4 + r];
                if (g != cur) {
                    if (cur >= 0 && run != 0.f)
                        atomicAdd(&praw[(size_t)cur * DIM + col], run);
                    run = 0.f; cur = g;
                }
                run += vv[r];
            }
            if (cur >= 0 && run != 0.f)
                atomicAdd(&praw[(size_t)cur * DIM + col], run);
        }
    }
    __syncthreads();
    if (tid < 2 * DIM)
        atomicAdd(&sums_part[(size_t)(blockIdx.x & (N_PART - 1)) * 2 * DIM + tid], sSum[tid]);
}

// ---------- final 2-layer MLP; pooled row assembled inline from partials
__global__ __launch_bounds__(192) void final_mlp(const float* __restrict__ sums_part,
    const float* __restrict__ praw,
    const float* __restrict__ gamma, const float* __restrict__ beta,
    const int* __restrict__ cntg,
    const float* __restrict__ PW1, const float* __restrict__ PB1,
    const float* __restrict__ PW2, const float* __restrict__ PB2,
    float* __restrict__ out) {
    __shared__ float row[D3];
    __shared__ float hid[D3];
    int g = blockIdx.x, j = threadIdx.x;
    {   // inline assemble_pooled for element (g, j)
        int L = j >> 6, c = j & 63;
        const float* sp = sums_part + (size_t)L * N_PART * 2 * DIM;
        float s = 0.f, q = 0.f;
#pragma unroll
        for (int p = 0; p < N_PART; p++) {
            s += sp[p * 2 * DIM + c];
            q += sp[p * 2 * DIM + DIM + c];
        }
        const float inv_n = 1.0f / (float)N_NODES;
        float mu  = s * inv_n;
        float var = q * inv_n - mu * mu;
        float sc  = gamma[L * DIM + c] / sqrtf(var + BN_EPS);
        float sh  = beta[L * DIM + c] - mu * sc;
        row[j] = fmaf(sc, praw[((size_t)L * N_GRAPHS + g) * DIM + c],
                      (float)cntg[g] * sh);
    }
    __syncthreads();
    float acc = PB1[j];
    for (int k = 0; k < D3; k++) acc = fmaf(row[k], PW1[k * D3 + j], acc);
    hid[j] = fmaxf(acc, 0.f);
    __syncthreads();
    float acc2 = PB2[j];
    for (int k = 0; k < D3; k++) acc2 = fmaf(hid[k], PW2[k * D3 + j], acc2);
    out[(size_t)g * D3 + j] = acc2;
}

extern "C" void kernel_launch(void* const* d_in, const int* in_sizes, int n_in,
                              void* d_out, int out_size, void* d_ws, size_t ws_size,
                              hipStream_t stream) {
    const float* x     = (const float*)d_in[0];
    const int*   ei    = (const int*)d_in[1];
    const int*   batch = (const int*)d_in[2];
    const float* W1    = (const float*)d_in[3];
    const float* B1    = (const float*)d_in[4];
    const float* W2    = (const float*)d_in[5];
    const float* B2    = (const float*)d_in[6];
    const float* gamma = (const float*)d_in[7];
    const float* beta  = (const float*)d_in[8];
    const float* PW1   = (const float*)d_in[9];
    const float* PB1   = (const float*)d_in[10];
    const float* PW2   = (const float*)d_in[11];
    const float* PB2   = (const float*)d_in[12];
    float* out = (float*)d_out;

    // -------- workspace layout (~38 MB of 256 MB)
    float*    bufA  = (float*)d_ws;                              // 3,200,000 f (zbB alias)
    unsigned short* zb = (unsigned short*)(bufA + (size_t)N_NODES * DIM); // 3,200,000 u16
    unsigned short* xb = zb + (size_t)N_NODES * DIM;             // 3,200,000 u16
    unsigned* ebuf  = (unsigned*)(xb + (size_t)N_NODES * DIM);   // 782*2048 u32
    int*      csr   = (int*)(ebuf + (size_t)NBKT * ECAP);        // 782*2048 i
    int*      rp2   = csr + NBKT * ECAP;                         // 782*65 -> 50,832
    unsigned short* wfrag = (unsigned short*)(rp2 + 50832);      // 49,152 u16
    int*      cntg  = (int*)(wfrag + 49152);                     // 256 i (written fully)
    // ---- zeroed region (one hipMemsetAsync): galloc(=bcnt) + sums_part + praw
    int*      galloc = cntg + N_GRAPHS;                          // 784 i (pad to even)
    float*    sums_part = (float*)(galloc + 784);                // 3*8*128 = 3,072 f
    float*    praw  = sums_part + N_LAYERS * N_PART * 2 * DIM;   // 49,152 f
    const size_t zbytes = (size_t)(784 + N_LAYERS * N_PART * 2 * DIM
                                   + N_LAYERS * N_GRAPHS * DIM) * 4;   // ~212 KB

    unsigned short* zbB = (unsigned short*)bufA;   // double-buffer for z

    const int* src = ei;
    const int* dst = ei + N_EDGES;

    // -------- zero galloc + accumulators, then ONE setup kernel
    hipMemsetAsync(galloc, 0, zbytes, stream);
    setup_scatter<<<NPB + CVT_BLOCKS + PREP_BLOCKS + 1, 256, 0, stream>>>(
        src, dst, galloc, ebuf, x, xb, W1, W2, wfrag, batch, cntg);

    // -------- fused layers: [sort]+gather(+prev BN)->MLP->(z + stats + pool)
    const int MB = NBKT;   // 782, block = bucket
    const unsigned short* inb[3]  = {xb, zb, zbB};
    unsigned short*       outb[3] = {zb, zbB, zb};   // L2 output unused
    for (int L = 0; L < N_LAYERS; ++L) {
        int write_z = (L < N_LAYERS - 1);
        layer_fused<<<MB, 256, 0, stream>>>(
            inb[L], outb[L], ebuf, galloc /* bcnt */, csr, rp2,
            (L == 0) ? (const float*)nullptr : sums_part + (size_t)(L - 1) * N_PART * 2 * DIM,
            gamma + (size_t)(L ? L - 1 : 0) * DIM,
            beta + (size_t)(L ? L - 1 : 0) * DIM,
            wfrag + (size_t)L * 2 * 8192, B1 + (size_t)L * DIM, B2 + (size_t)L * DIM,
            sums_part + (size_t)L * N_PART * 2 * DIM,
            praw + (size_t)L * N_GRAPHS * DIM, batch, write_z, (L == 0) ? 1 : 0);
    }

    final_mlp<<<N_GRAPHS, 192, 0, stream>>>(
        sums_part, praw, gamma, beta, cntg, PW1, PB1, PW2, PB2, out);
}

// Round 10
// 198.943 us; speedup vs baseline: 1.0484x; 1.0484x over previous
//
#include <hip/hip_runtime.h>

#define N_NODES 50000
#define N_EDGES 800000
#define DIM 64
#define N_LAYERS 3
#define N_GRAPHS 256
#define BN_EPS 1e-5f
#define D3 (DIM * N_LAYERS)
#define N_PART 8
#define NBKT 782          // ceil(50000/64) destination buckets
#define NPB 196           // partition blocks (4096 edges each)
#define ECAP 2048         // fixed capacity per bucket (mean 1023, sigma ~32)
#define CVT_BLOCKS 3125   // convert_x blocks (800,000 float4 / 256)
#define PREP_BLOCKS 96    // prep_weights blocks (24,576 / 256)
#define SZ_STR 68

typedef __attribute__((ext_vector_type(8))) short short8;
typedef __attribute__((ext_vector_type(4))) float floatx4;

// ---------------------------------------------------------- bf16 split utils
__device__ inline unsigned short bf16_rn(float f) {
    unsigned u = __float_as_uint(f);
    u += 0x7FFF + ((u >> 16) & 1);
    return (unsigned short)(u >> 16);
}
__device__ inline float bf16_f(unsigned short b) {
    return __uint_as_float(((unsigned)b) << 16);
}
__device__ inline void split8(float4 a, float4 b, short8* hi, short8* lo) {
    float v[8] = {a.x, a.y, a.z, a.w, b.x, b.y, b.z, b.w};
#pragma unroll
    for (int i = 0; i < 8; i++) {
        unsigned short h = bf16_rn(v[i]);
        (*hi)[i] = (short)h;
        (*lo)[i] = (short)bf16_rn(v[i] - bf16_f(h));
    }
}

// ===== single-pass setup: LDS hist -> atomic chunk reservation -> chunked
// scatter (blocks [0,NPB)) + x->bf16 convert + weight prep + cntg.
// galloc[] (pre-zeroed) accumulates bucket totals; its final value == bcnt.
__global__ __launch_bounds__(256) void setup_scatter(
    const int* __restrict__ src, const int* __restrict__ dst,
    int* __restrict__ galloc,
    unsigned* __restrict__ ebuf,
    const float* __restrict__ x, unsigned short* __restrict__ xb,
    const float* __restrict__ W1, const float* __restrict__ W2,
    unsigned short* __restrict__ wf,
    const int* __restrict__ batch, int* __restrict__ cntg) {
    int blk = blockIdx.x, tid = threadIdx.x;

    if (blk < NPB) {                      // ---- hist + reserve + scatter
        __shared__ int hcnt[NBKT];
        __shared__ int loff[NBKT];
        for (int i = tid; i < NBKT; i += 256) hcnt[i] = 0;
        __syncthreads();
        int base = blk * 4096;
#pragma unroll
        for (int k = 0; k < 16; k++) {
            int e = base + k * 256 + tid;
            if (e < N_EDGES) atomicAdd(&hcnt[dst[e] >> 6], 1);   // LDS atomic
        }
        __syncthreads();
        for (int i = tid; i < NBKT; i += 256) {
            int c = hcnt[i];
            loff[i] = c ? atomicAdd(&galloc[i], c) : 0;   // global chunk reserve
        }
        __syncthreads();
#pragma unroll
        for (int k = 0; k < 16; k++) {
            int e = base + k * 256 + tid;
            if (e < N_EDGES) {
                int d = dst[e];
                int b = d >> 6;
                int pos = atomicAdd(&loff[b], 1);          // LDS atomic
                ebuf[(size_t)b * ECAP + pos] = ((unsigned)src[e] << 6) | (unsigned)(d & 63);
            }
        }
        return;
    }
    int sb = blk - NPB;
    if (sb < CVT_BLOCKS) {                // ---- convert x to bf16
        int i = sb * 256 + tid;
        float4 v = ((const float4*)x)[i];
        ushort4 o;
        o.x = bf16_rn(v.x); o.y = bf16_rn(v.y);
        o.z = bf16_rn(v.z); o.w = bf16_rn(v.w);
        ((ushort4*)xb)[i] = o;
        return;
    }
    sb -= CVT_BLOCKS;
    if (sb < PREP_BLOCKS) {               // ---- pack weight fragments
        int idx = sb * 256 + tid;
        int j    = idx & 7;
        int lane = (idx >> 3) & 63;
        int ks   = (idx >> 9) & 1;
        int nt   = (idx >> 10) & 3;
        int gemm = (idx >> 12) & 1;
        int layer = idx >> 13;
        int n = nt * 16 + (lane & 15);
        int k = ks * 32 + (lane >> 4) * 8 + j;
        const float* W = (gemm ? W2 : W1) + (size_t)layer * DIM * DIM;
        float w = W[k * DIM + n];
        unsigned short hi = bf16_rn(w);
        unsigned short lo = bf16_rn(w - bf16_f(hi));
        size_t base = ((size_t)layer * 2 + gemm) * 8192;
        int f = nt * 2 + ks;
        wf[base + f * 512 + lane * 8 + j]        = hi;
        wf[base + 4096 + f * 512 + lane * 8 + j] = lo;
        return;
    }
    // ---- per-graph node counts via binary search (batch sorted)
    int g = tid;
    int lo = 0, hi = N_NODES;
    while (lo < hi) { int mid = (lo + hi) >> 1; if (batch[mid] < g) lo = mid + 1; else hi = mid; }
    int start = lo;
    lo = 0; hi = N_NODES;
    while (lo < hi) { int mid = (lo + hi) >> 1; if (batch[mid] < g + 1) lo = mid + 1; else hi = mid; }
    cntg[g] = lo - start;
}

// ===================== fused per-layer kernel =====================
// Block = 64 nodes = one CSR bucket. LDS ~27.9 KB, 4 blocks/CU (R8 config).
// Gather: 8-deep unroll for ILP on the dependent-load chain; sCsr staged
// BEFORE the BN preamble so its loads overlap the spPrev reads + barriers.
// H-tile overlays sZ (wave w's H rows == wave w's own sZ rows).
__global__ __launch_bounds__(256, 4) void layer_fused(
    const unsigned short* __restrict__ hb,   // input node rows (bf16)
    unsigned short* __restrict__ zb,         // output node rows (bf16), if write_z
    const unsigned* __restrict__ ebuf, const int* __restrict__ bcnt,
    int* __restrict__ csr, int* __restrict__ rp2,
    const float* __restrict__ spPrev,        // null for layer 0
    const float* __restrict__ gammaP, const float* __restrict__ betaP,
    const unsigned short* __restrict__ wfL,
    const float* __restrict__ B1, const float* __restrict__ B2,
    float* __restrict__ sums_part, float* __restrict__ praw,
    const int* __restrict__ batch, int write_z, int do_sort) {
    __shared__ __align__(16) float sZ[64 * SZ_STR];   // 17408 B (gather out + H overlay)
    __shared__ int   sCsr[ECAP];                      // 8192 B
    __shared__ float sSS[2 * DIM];
    __shared__ float sSum[2 * DIM];
    __shared__ int   sRP[65];               // bucket-relative row pointers
    __shared__ int   sBatch[64];
    __shared__ int   cnt[64], basea[64], fill[64];

    int tid = threadIdx.x;
    int blk = blockIdx.x;
    int blk0 = blk * 64;

    if (tid < 2 * DIM) sSum[tid] = 0.f;
    if (tid < 64) sBatch[tid] = (blk0 + tid < N_NODES) ? batch[blk0 + tid] : -1;

    if (do_sort) {
        // ---------------- bucket counting sort (layer 0) ----------------
        int T = bcnt[blk];
        unsigned* ent = (unsigned*)sZ;       // raw-entry staging (8KB of 17.4KB)
        const unsigned* eb = ebuf + (size_t)blk * ECAP;
        if (tid < 64) cnt[tid] = 0;
        for (int i = tid; i < T; i += 256) ent[i] = eb[i];
        __syncthreads();
        for (int i = tid; i < T; i += 256) atomicAdd(&cnt[ent[i] & 63], 1);
        __syncthreads();
        if (tid < 64) {
            int v = cnt[tid], xp = v;
#pragma unroll
            for (int off = 1; off < 64; off <<= 1) {
                int y = __shfl_up(xp, off);
                if (tid >= off) xp += y;
            }
            basea[tid] = xp - v;
            fill[tid] = 0;
            sRP[tid] = xp - v;
            rp2[blk * 65 + tid] = blk * ECAP + xp - v;
            if (tid == 63) { sRP[64] = xp; rp2[blk * 65 + 64] = blk * ECAP + xp; }
        }
        __syncthreads();
        for (int i = tid; i < T; i += 256) {
            unsigned e = ent[i];
            int c = e & 63;
            int pos = basea[c] + atomicAdd(&fill[c], 1);
            int s = (int)(e >> 6);
            sCsr[pos] = s;
            csr[blk * ECAP + pos] = s;       // write-through for layers 1,2
        }
        __syncthreads();
    } else {
        // ---- stage csr slice FIRST (count from bcnt: no rp2 dependence),
        //      so these loads overlap the BN preamble's global reads.
        int T = bcnt[blk];
        const int* cs = csr + (size_t)blk * ECAP;
        for (int i = tid; i < T; i += 256) sCsr[i] = cs[i];
        if (tid < 65) sRP[tid] = rp2[blk * 65 + tid] - blk * ECAP;
        float* sRed = sZ;                    // scratch (sZ rewritten by gather)
        if (spPrev && tid < 2 * DIM) {
            float s = 0.f;
#pragma unroll
            for (int p = 0; p < N_PART; p++) s += spPrev[p * 2 * DIM + tid];
            sRed[tid] = s;
        }
        __syncthreads();
        if (spPrev && tid < DIM) {
            const float inv_n = 1.0f / (float)N_NODES;
            float mu  = sRed[tid] * inv_n;
            float var = sRed[DIM + tid] * inv_n - mu * mu;
            float sc  = gammaP[tid] / sqrtf(var + BN_EPS);
            sSS[tid]       = sc;
            sSS[DIM + tid] = betaP[tid] - mu * sc;
        }
        __syncthreads();
    }

    // ---------------- Phase B: gather into sZ (8-deep unroll) ----------------
    {
        int c8 = tid & 7, grp = tid >> 3;    // 32 groups of 8 lanes
        const bool aff = (spPrev != nullptr);
#pragma unroll
        for (int p = 0; p < 2; ++p) {
            int t = grp + 32 * p;
            int nodeg = blk0 + t;
            float a[8];
            if (nodeg < N_NODES) {
                int e0 = sRP[t], end = sRP[t + 1];
                short8 sv = *(const short8*)&hb[(size_t)nodeg * DIM + c8 * 8];
#pragma unroll
                for (int i = 0; i < 8; i++) a[i] = bf16_f((unsigned short)sv[i]);
                int e = e0;
                for (; e + 8 <= end; e += 8) {
                    int i0 = sCsr[e],     i1 = sCsr[e + 1], i2 = sCsr[e + 2], i3 = sCsr[e + 3];
                    int i4 = sCsr[e + 4], i5 = sCsr[e + 5], i6 = sCsr[e + 6], i7 = sCsr[e + 7];
                    short8 r0 = *(const short8*)&hb[(size_t)i0 * DIM + c8 * 8];
                    short8 r1 = *(const short8*)&hb[(size_t)i1 * DIM + c8 * 8];
                    short8 r2 = *(const short8*)&hb[(size_t)i2 * DIM + c8 * 8];
                    short8 r3 = *(const short8*)&hb[(size_t)i3 * DIM + c8 * 8];
                    short8 r4 = *(const short8*)&hb[(size_t)i4 * DIM + c8 * 8];
                    short8 r5 = *(const short8*)&hb[(size_t)i5 * DIM + c8 * 8];
                    short8 r6 = *(const short8*)&hb[(size_t)i6 * DIM + c8 * 8];
                    short8 r7 = *(const short8*)&hb[(size_t)i7 * DIM + c8 * 8];
#pragma unroll
                    for (int i = 0; i < 8; i++)
                        a[i] += ((bf16_f((unsigned short)r0[i]) + bf16_f((unsigned short)r1[i]))
                              +  (bf16_f((unsigned short)r2[i]) + bf16_f((unsigned short)r3[i])))
                              + ((bf16_f((unsigned short)r4[i]) + bf16_f((unsigned short)r5[i]))
                              +  (bf16_f((unsigned short)r6[i]) + bf16_f((unsigned short)r7[i])));
                }
                for (; e + 4 <= end; e += 4) {
                    int i0 = sCsr[e], i1 = sCsr[e + 1], i2 = sCsr[e + 2], i3 = sCsr[e + 3];
                    short8 r0 = *(const short8*)&hb[(size_t)i0 * DIM + c8 * 8];
                    short8 r1 = *(const short8*)&hb[(size_t)i1 * DIM + c8 * 8];
                    short8 r2 = *(const short8*)&hb[(size_t)i2 * DIM + c8 * 8];
                    short8 r3 = *(const short8*)&hb[(size_t)i3 * DIM + c8 * 8];
#pragma unroll
                    for (int i = 0; i < 8; i++)
                        a[i] += (bf16_f((unsigned short)r0[i]) + bf16_f((unsigned short)r1[i]))
                              + (bf16_f((unsigned short)r2[i]) + bf16_f((unsigned short)r3[i]));
                }
                for (; e < end; ++e) {
                    int i0 = sCsr[e];
                    short8 r0 = *(const short8*)&hb[(size_t)i0 * DIM + c8 * 8];
#pragma unroll
                    for (int i = 0; i < 8; i++) a[i] += bf16_f((unsigned short)r0[i]);
                }
                if (aff) {
                    float degf = 1.f + (float)(end - e0);
#pragma unroll
                    for (int i = 0; i < 8; i++)
                        a[i] = fmaf(a[i], sSS[c8 * 8 + i], degf * sSS[DIM + c8 * 8 + i]);
                }
            } else {
#pragma unroll
                for (int i = 0; i < 8; i++) a[i] = 0.f;
            }
            float4 o1, o2;
            o1.x = a[0]; o1.y = a[1]; o1.z = a[2]; o1.w = a[3];
            o2.x = a[4]; o2.y = a[5]; o2.z = a[6]; o2.w = a[7];
            *(float4*)&sZ[t * SZ_STR + c8 * 8]     = o1;
            *(float4*)&sZ[t * SZ_STR + c8 * 8 + 4] = o2;
        }
    }
    __syncthreads();

    // ---------------- Phase C: MFMA MLP ----------------
    int wave = tid >> 6, lane = tid & 63;
    int m = lane & 15, quad = lane >> 4;
    int row0 = blk0 + wave * 16;
    int lrow = wave * 16 + m;

    float4 a0 = *(const float4*)&sZ[lrow * SZ_STR + quad * 8];
    float4 a1 = *(const float4*)&sZ[lrow * SZ_STR + quad * 8 + 4];
    float4 a2 = *(const float4*)&sZ[lrow * SZ_STR + 32 + quad * 8];
    float4 a3 = *(const float4*)&sZ[lrow * SZ_STR + 32 + quad * 8 + 4];
    short8 Ah0, Al0, Ah1, Al1;
    split8(a0, a1, &Ah0, &Al0);
    split8(a2, a3, &Ah1, &Al1);

    floatx4 acc[4];
#pragma unroll
    for (int nt = 0; nt < 4; nt++) acc[nt] = (floatx4){0.f, 0.f, 0.f, 0.f};
#pragma unroll
    for (int nt = 0; nt < 4; nt++) {
#pragma unroll
        for (int ks = 0; ks < 2; ks++) {
            const short8 Bh = *(const short8*)(wfL + (nt * 2 + ks) * 512 + lane * 8);
            const short8 Bl = *(const short8*)(wfL + 4096 + (nt * 2 + ks) * 512 + lane * 8);
            short8 Ahf = ks ? Ah1 : Ah0;
            short8 Alf = ks ? Al1 : Al0;
            acc[nt] = __builtin_amdgcn_mfma_f32_16x16x32_bf16(Ahf, Bh, acc[nt], 0, 0, 0);
            acc[nt] = __builtin_amdgcn_mfma_f32_16x16x32_bf16(Ahf, Bl, acc[nt], 0, 0, 0);
            acc[nt] = __builtin_amdgcn_mfma_f32_16x16x32_bf16(Alf, Bh, acc[nt], 0, 0, 0);
        }
    }

    // all waves' A-fragments are in registers; safe to overlay H on own sZ rows
    __syncthreads();
    float* Hs = sZ + (size_t)(wave * 16) * SZ_STR;   // wave w's own 16 rows
#pragma unroll
    for (int nt = 0; nt < 4; nt++) {
        int col = nt * 16 + m;
        float b = B1[col];
#pragma unroll
        for (int r = 0; r < 4; r++) {
            int lr = quad * 4 + r;
            Hs[lr * SZ_STR + col] = fmaxf(acc[nt][r] + b, 0.f);
        }
    }
    float4 h0 = *(const float4*)&Hs[m * SZ_STR + quad * 8];
    float4 h1 = *(const float4*)&Hs[m * SZ_STR + quad * 8 + 4];
    float4 h2 = *(const float4*)&Hs[m * SZ_STR + 32 + quad * 8];
    float4 h3 = *(const float4*)&Hs[m * SZ_STR + 32 + quad * 8 + 4];
    short8 Hh0, Hl0, Hh1, Hl1;
    split8(h0, h1, &Hh0, &Hl0);
    split8(h2, h3, &Hh1, &Hl1);

    floatx4 acc2[4];
#pragma unroll
    for (int nt = 0; nt < 4; nt++) acc2[nt] = (floatx4){0.f, 0.f, 0.f, 0.f};
    const unsigned short* wg2 = wfL + 8192;
#pragma unroll
    for (int nt = 0; nt < 4; nt++) {
#pragma unroll
        for (int ks = 0; ks < 2; ks++) {
            const short8 Bh = *(const short8*)(wg2 + (nt * 2 + ks) * 512 + lane * 8);
            const short8 Bl = *(const short8*)(wg2 + 4096 + (nt * 2 + ks) * 512 + lane * 8);
            short8 Ahf = ks ? Hh1 : Hh0;
            short8 Alf = ks ? Hl1 : Hl0;
            acc2[nt] = __builtin_amdgcn_mfma_f32_16x16x32_bf16(Ahf, Bh, acc2[nt], 0, 0, 0);
            acc2[nt] = __builtin_amdgcn_mfma_f32_16x16x32_bf16(Ahf, Bl, acc2[nt], 0, 0, 0);
            acc2[nt] = __builtin_amdgcn_mfma_f32_16x16x32_bf16(Alf, Bh, acc2[nt], 0, 0, 0);
        }
    }

    // ---- epilogue: bf16 z write + BN partials + per-graph raw pooling
    int widx = wave * 16;
    int gfirst = sBatch[widx], glast = sBatch[widx + 15];
    bool uni = (gfirst == glast) && (gfirst >= 0);
#pragma unroll
    for (int nt = 0; nt < 4; nt++) {
        int col = nt * 16 + m;
        float b = B2[col];
        float vv[4];
        float s = 0.f, s2 = 0.f;
#pragma unroll
        for (int r = 0; r < 4; r++) {
            int gr = row0 + quad * 4 + r;
            float v = fmaxf(acc2[nt][r] + b, 0.f);
            if (gr < N_NODES) {
                if (write_z) zb[(size_t)gr * DIM + col] = bf16_rn(v);
                s += v;
                s2 = fmaf(v, v, s2);
                vv[r] = v;
            } else {
                vv[r] = 0.f;
            }
        }
        float sf = s, s2f = s2;
        sf  += __shfl_xor(sf, 16);  sf  += __shfl_xor(sf, 32);
        s2f += __shfl_xor(s2f, 16); s2f += __shfl_xor(s2f, 32);
        if (quad == 0) {
            atomicAdd(&sSum[col], sf);
            atomicAdd(&sSum[DIM + col], s2f);
            if (uni) atomicAdd(&praw[(size_t)gfirst * DIM + col], sf);
        }
        if (!uni) {
            int cur = -1; float run = 0.f;
#pragma unroll
            for (int r = 0; r < 4; r++) {
                int g = sBatch[widx + quad * 4 + r];
                if (g != cur) {
                    if (cur >= 0 && run != 0.f)
                        atomicAdd(&praw[(size_t)cur * DIM + col], run);
                    run = 0.f; cur = g;
                }
                run += vv[r];
            }
            if (cur >= 0 && run != 0.f)
                atomicAdd(&praw[(size_t)cur * DIM + col], run);
        }
    }
    __syncthreads();
    if (tid < 2 * DIM)
        atomicAdd(&sums_part[(size_t)(blockIdx.x & (N_PART - 1)) * 2 * DIM + tid], sSum[tid]);
}

// ---------- final 2-layer MLP; pooled row assembled inline from partials
__global__ __launch_bounds__(192) void final_mlp(const float* __restrict__ sums_part,
    const float* __restrict__ praw,
    const float* __restrict__ gamma, const float* __restrict__ beta,
    const int* __restrict__ cntg,
    const float* __restrict__ PW1, const float* __restrict__ PB1,
    const float* __restrict__ PW2, const float* __restrict__ PB2,
    float* __restrict__ out) {
    __shared__ float row[D3];
    __shared__ float hid[D3];
    int g = blockIdx.x, j = threadIdx.x;
    {   // inline assemble_pooled for element (g, j)
        int L = j >> 6, c = j & 63;
        const float* sp = sums_part + (size_t)L * N_PART * 2 * DIM;
        float s = 0.f, q = 0.f;
#pragma unroll
        for (int p = 0; p < N_PART; p++) {
            s += sp[p * 2 * DIM + c];
            q += sp[p * 2 * DIM + DIM + c];
        }
        const float inv_n = 1.0f / (float)N_NODES;
        float mu  = s * inv_n;
        float var = q * inv_n - mu * mu;
        float sc  = gamma[L * DIM + c] / sqrtf(var + BN_EPS);
        float sh  = beta[L * DIM + c] - mu * sc;
        row[j] = fmaf(sc, praw[((size_t)L * N_GRAPHS + g) * DIM + c],
                      (float)cntg[g] * sh);
    }
    __syncthreads();
    float acc = PB1[j];
    for (int k = 0; k < D3; k++) acc = fmaf(row[k], PW1[k * D3 + j], acc);
    hid[j] = fmaxf(acc, 0.f);
    __syncthreads();
    float acc2 = PB2[j];
    for (int k = 0; k < D3; k++) acc2 = fmaf(hid[k], PW2[k * D3 + j], acc2);
    out[(size_t)g * D3 + j] = acc2;
}

extern "C" void kernel_launch(void* const* d_in, const int* in_sizes, int n_in,
                              void* d_out, int out_size, void* d_ws, size_t ws_size,
                              hipStream_t stream) {
    const float* x     = (const float*)d_in[0];
    const int*   ei    = (const int*)d_in[1];
    const int*   batch = (const int*)d_in[2];
    const float* W1    = (const float*)d_in[3];
    const float* B1    = (const float*)d_in[4];
    const float* W2    = (const float*)d_in[5];
    const float* B2    = (const float*)d_in[6];
    const float* gamma = (const float*)d_in[7];
    const float* beta  = (const float*)d_in[8];
    const float* PW1   = (const float*)d_in[9];
    const float* PB1   = (const float*)d_in[10];
    const float* PW2   = (const float*)d_in[11];
    const float* PB2   = (const float*)d_in[12];
    float* out = (float*)d_out;

    // -------- workspace layout (~38 MB of 256 MB)
    float*    bufA  = (float*)d_ws;                              // 3,200,000 f (zbB alias)
    unsigned short* zb = (unsigned short*)(bufA + (size_t)N_NODES * DIM); // 3,200,000 u16
    unsigned short* xb = zb + (size_t)N_NODES * DIM;             // 3,200,000 u16
    unsigned* ebuf  = (unsigned*)(xb + (size_t)N_NODES * DIM);   // 782*2048 u32
    int*      csr   = (int*)(ebuf + (size_t)NBKT * ECAP);        // 782*2048 i
    int*      rp2   = csr + NBKT * ECAP;                         // 782*65 -> 50,832
    unsigned short* wfrag = (unsigned short*)(rp2 + 50832);      // 49,152 u16
    int*      cntg  = (int*)(wfrag + 49152);                     // 256 i (written fully)
    // ---- zeroed region (one hipMemsetAsync): galloc(=bcnt) + sums_part + praw
    int*      galloc = cntg + N_GRAPHS;                          // 784 i (pad to even)
    float*    sums_part = (float*)(galloc + 784);                // 3*8*128 = 3,072 f
    float*    praw  = sums_part + N_LAYERS * N_PART * 2 * DIM;   // 49,152 f
    const size_t zbytes = (size_t)(784 + N_LAYERS * N_PART * 2 * DIM
                                   + N_LAYERS * N_GRAPHS * DIM) * 4;   // ~212 KB

    unsigned short* zbB = (unsigned short*)bufA;   // double-buffer for z

    const int* src = ei;
    const int* dst = ei + N_EDGES;

    // -------- zero galloc + accumulators, then ONE setup kernel
    hipMemsetAsync(galloc, 0, zbytes, stream);
    setup_scatter<<<NPB + CVT_BLOCKS + PREP_BLOCKS + 1, 256, 0, stream>>>(
        src, dst, galloc, ebuf, x, xb, W1, W2, wfrag, batch, cntg);

    // -------- fused layers: [sort]+gather(+prev BN)->MLP->(z + stats + pool)
    const int MB = NBKT;   // 782, block = bucket
    const unsigned short* inb[3]  = {xb, zb, zbB};
    unsigned short*       outb[3] = {zb, zbB, zb};   // L2 output unused
    for (int L = 0; L < N_LAYERS; ++L) {
        int write_z = (L < N_LAYERS - 1);
        layer_fused<<<MB, 256, 0, stream>>>(
            inb[L], outb[L], ebuf, galloc /* bcnt */, csr, rp2,
            (L == 0) ? (const float*)nullptr : sums_part + (size_t)(L - 1) * N_PART * 2 * DIM,
            gamma + (size_t)(L ? L - 1 : 0) * DIM,
            beta + (size_t)(L ? L - 1 : 0) * DIM,
            wfrag + (size_t)L * 2 * 8192, B1 + (size_t)L * DIM, B2 + (size_t)L * DIM,
            sums_part + (size_t)L * N_PART * 2 * DIM,
            praw + (size_t)L * N_GRAPHS * DIM, batch, write_z, (L == 0) ? 1 : 0);
    }

    final_mlp<<<N_GRAPHS, 192, 0, stream>>>(
        sums_part, praw, gamma, beta, cntg, PW1, PB1, PW2, PB2, out);
}